// Round 1
// baseline (678.417 us; speedup 1.0000x reference)
//
#include <hip/hip_runtime.h>

// Problem constants (from reference)
#define Bx 4
#define Nn 10000
#define Ee 160000
#define Qq 256
#define Dd 128
#define Mm 64
#define Uu 126
#define Hh 128
#define Pp 7

typedef unsigned short u16;
typedef __bf16 bf16x8 __attribute__((ext_vector_type(8)));
typedef float f32x4 __attribute__((ext_vector_type(4)));

__device__ __forceinline__ float b2f(u16 h){
  unsigned u = ((unsigned)h) << 16; float f; __builtin_memcpy(&f, &u, 4); return f;
}
__device__ __forceinline__ u16 f2b(float f){
  unsigned u; __builtin_memcpy(&u, &f, 4);
  u = (u + 0x7FFFu + ((u >> 16) & 1u)) >> 16;   // RNE; exact round-trip for bf16 inputs
  return (u16)u;
}
// flag==1: input arrays are bf16 (ushort); flag==0: float32
__device__ __forceinline__ float ldin(const void* p, long i, int flag){
  return flag ? b2f(((const u16*)p)[i]) : ((const float*)p)[i];
}
__device__ __forceinline__ void acc2bf(float& a0, float& a1, unsigned v){
  a0 += b2f((u16)(v & 0xffffu));
  a1 += b2f((u16)(v >> 16));
}

// ---------------- dtype probe ----------------
// nodes_states ~ N(0,1). Read head as bf16: true-bf16 -> ~all |v| in (2^-10,32);
// f32 reinterpret -> only ~half (high words) plausible. Threshold 240/256.
__global__ void probe_kernel(const void* in0, int* flag){
  if (threadIdx.x == 0 && blockIdx.x == 0){
    const u16* p = (const u16*)in0;
    int cnt = 0;
    for (int i = 0; i < 256; i++){
      float a = fabsf(b2f(p[i]));
      if (a > 0.0009765625f && a < 32.0f) cnt++;
    }
    *flag = (cnt >= 240) ? 1 : 0;
  }
}

// ---------------- weight prep: convert + swizzle to MFMA B-frag layout ----------------
// B-frag layout per 16x16x32 MFMA: lane holds B[k_oct*8+j][n], so store [k/8][n][k%8].
__global__ void prep_kernel(const void* w1e, const void* b1e, const void* w2e, const void* b2e,
                            const void* w1n, const void* b1n, const void* w2n, const void* b2n,
                            const int* __restrict__ flag,
                            u16* w1e_s, u16* w2e_s, u16* w1n_s, u16* w2n_s,
                            float* b1e_f, float* b2e_f, float* b1n_f, float* b2n_f)
{
  int f = *flag;
  for (int idx = blockIdx.x * blockDim.x + threadIdx.x; idx < 82368; idx += gridDim.x * blockDim.x){
    if (idx < 32768){                                   // w1e (256,128)
      int k = idx >> 7, h = idx & 127;
      w1e_s[(k >> 3) * 1024 + h * 8 + (k & 7)] = f2b(ldin(w1e, idx, f));
    } else if (idx < 40960){                            // w2e (128,64)
      int i2 = idx - 32768; int k = i2 >> 6, m2 = i2 & 63;
      w2e_s[(k >> 3) * 512 + m2 * 8 + (k & 7)] = f2b(ldin(w2e, i2, f));
    } else if (idx < 65536){                            // w1n (192,128)
      int i2 = idx - 40960; int k = i2 >> 7, h = i2 & 127;
      w1n_s[(k >> 3) * 1024 + h * 8 + (k & 7)] = f2b(ldin(w1n, i2, f));
    } else if (idx < 81920){                            // w2n (128,126) padded to 128 cols
      int i2 = idx - 65536; int k = i2 >> 7, u = i2 & 127;
      float v = (u < 126) ? ldin(w2n, (long)k * 126 + u, f) : 0.f;
      w2n_s[(k >> 3) * 1024 + u * 8 + (k & 7)] = f2b(v);
    } else if (idx < 82048){ b1e_f[idx - 81920] = ldin(b1e, idx - 81920, f); }
    else if (idx < 82112){ b2e_f[idx - 82048] = ldin(b2e, idx - 82048, f); }
    else if (idx < 82240){ b1n_f[idx - 82112] = ldin(b1n, idx - 82112, f); }
    else { int j = idx - 82240; b2n_f[j] = (j < 126) ? ldin(b2n, j, f) : 0.f; }
  }
}

// ---------------- init: f32 master states + bf16 mirror ----------------
__global__ void init_states_kernel(const void* in0, const int* __restrict__ flag,
                                   float* __restrict__ sf, u16* __restrict__ sbm)
{
  int f = *flag;
  const long total = (long)Bx * Nn * Dd;
  for (long i = (long)blockIdx.x * blockDim.x + threadIdx.x; i < total; i += (long)gridDim.x * blockDim.x){
    float v = ldin(in0, i, f);
    sf[i] = v; sbm[i] = f2b(v);
  }
}

// ---------------- CSR build ----------------
__global__ void count_kernel(const int* __restrict__ snk, int* __restrict__ cnt){
  int i = blockIdx.x * blockDim.x + threadIdx.x;
  if (i < Ee) atomicAdd(&cnt[snk[i]], 1);
}
__global__ void scan_kernel(const int* __restrict__ cnt, int* __restrict__ rowp){
  __shared__ int tot[1024];
  int t = threadIdx.x;
  int base = t * 10;
  int local[10]; int s = 0;
  #pragma unroll
  for (int i = 0; i < 10; i++){
    int v = (base + i < Nn) ? cnt[base + i] : 0;
    local[i] = s; s += v;
  }
  tot[t] = s;
  __syncthreads();
  for (int o = 1; o < 1024; o <<= 1){
    int v = (t >= o) ? tot[t - o] : 0;
    __syncthreads();
    tot[t] += v;
    __syncthreads();
  }
  int prefix = (t == 0) ? 0 : tot[t - 1];
  #pragma unroll
  for (int i = 0; i < 10; i++)
    if (base + i < Nn) rowp[base + i] = prefix + local[i];
  if (t == 1023) rowp[Nn] = tot[1023];
}
__global__ void fill_kernel(const int* __restrict__ snk, const int* __restrict__ rowp,
                            int* __restrict__ cnt, int* __restrict__ eidx){
  int i = blockIdx.x * blockDim.x + threadIdx.x;
  if (i < Ee){
    int s = snk[i];
    int p = rowp[s] + atomicAdd(&cnt[s], 1);
    eidx[p] = i;
  }
}

// ---------------- edge MLP: msg = relu([s_src|s_snk]@w1e+b1)@w2e+b2 ----------------
// 512 thr = 8 waves, tile = 128 edges, wave owns 16 rows. LDS <= 64KB:
//   w1e staged in two 32KB K-halves; w2e B-frags from global (L1); Y split in 2 col phases.
__global__ __launch_bounds__(512) void edge_kernel(
  const u16* __restrict__ sbm, const int* __restrict__ src, const int* __restrict__ snk,
  const u16* __restrict__ w1s, const u16* __restrict__ w2s,
  const float* __restrict__ b1f, const float* __restrict__ b2f2,
  u16* __restrict__ msg, int b0)
{
  __shared__ __align__(16) u16 w1h[16384];     // 32KB: one K-half of w1e, swizzled
  __shared__ __align__(16) u16 Yt[128 * 72];   // 18KB: hidden half (64 cols), stride 72 (2-way free)
  __shared__ float b1l[128];
  __shared__ float b2l[64];
  int tid = threadIdx.x;
  if (tid < 128) b1l[tid] = b1f[tid];
  else if (tid < 192) b2l[tid - 128] = b2f2[tid - 128];

  int tile = blockIdx.x;
  int bl = tile / 1250;
  int e0 = (tile % 1250) * 128;
  int b = b0 + bl;
  int w = tid >> 6, lane = tid & 63, m = lane & 15, quad = lane >> 4;
  int e = e0 + w * 16 + m;
  int nsrc = src[e], nsnk = snk[e];
  const u16* sbase = sbm + (((size_t)b * Nn) << 7);

  f32x4 acc1[8];
  const f32x4 z4 = {0.f, 0.f, 0.f, 0.f};
  #pragma unroll
  for (int ct = 0; ct < 8; ct++) acc1[ct] = z4;

  #pragma unroll 1
  for (int half = 0; half < 2; half++){
    __syncthreads();                               // prev reads of w1h done
    {
      const uint4* g = (const uint4*)(w1s + half * 16384);
      uint4* l = (uint4*)w1h;
      #pragma unroll
      for (int i = 0; i < 4; i++) l[tid + i * 512] = g[tid + i * 512];
    }
    __syncthreads();
    // A rows: gathered node states (k<128 -> src, else snk)
    const u16* arow = sbase + (((size_t)(half ? nsnk : nsrc)) << 7);
    #pragma unroll
    for (int lk = 0; lk < 4; lk++){
      bf16x8 a = *(const bf16x8*)(arow + lk * 32 + quad * 8);
      #pragma unroll
      for (int ct = 0; ct < 8; ct++){
        bf16x8 bv = *(const bf16x8*)(w1h + (((lk * 4 + quad) << 7) + ct * 16 + m) * 8);
        acc1[ct] = __builtin_amdgcn_mfma_f32_16x16x32_bf16(a, bv, acc1[ct], 0, 0, 0);
      }
    }
  }

  // layer 2, hidden split in two 64-col phases (Y rows are wave-private: no barrier)
  f32x4 acc2[4];
  #pragma unroll
  for (int ct = 0; ct < 4; ct++) acc2[ct] = z4;
  #pragma unroll 1
  for (int ph = 0; ph < 2; ph++){
    #pragma unroll
    for (int c = 0; c < 4; c++){
      int ct = ph * 4 + c;
      #pragma unroll
      for (int i = 0; i < 4; i++){
        float v = acc1[ct][i] + b1l[ct * 16 + m];
        v = v > 0.f ? v : 0.f;
        Yt[(w * 16 + quad * 4 + i) * 72 + c * 16 + m] = f2b(v);
      }
    }
    #pragma unroll
    for (int lk = 0; lk < 2; lk++){
      int ko = ph * 2 + lk;
      bf16x8 a2 = *(const bf16x8*)(Yt + (w * 16 + m) * 72 + lk * 32 + quad * 8);
      #pragma unroll
      for (int ct = 0; ct < 4; ct++){
        bf16x8 bv = *(const bf16x8*)(w2s + (((ko * 4 + quad) << 6) + ct * 16 + m) * 8);
        acc2[ct] = __builtin_amdgcn_mfma_f32_16x16x32_bf16(a2, bv, acc2[ct], 0, 0, 0);
      }
    }
  }
  // store msg (bf16) — C/D layout: row=quad*4+i, col=ct*16+m
  size_t mrow = (((size_t)bl * Ee) + e0 + w * 16) << 6;
  #pragma unroll
  for (int ct = 0; ct < 4; ct++){
    #pragma unroll
    for (int i = 0; i < 4; i++){
      float v = acc2[ct][i] + b2l[ct * 16 + m];
      msg[mrow + ((size_t)(quad * 4 + i) << 6) + ct * 16 + m] = f2b(v);
    }
  }
}

// ---------------- node MLP: gather msgs (CSR), [inc|state]@w1n->relu->@w2n, states[2:] += upd
__global__ __launch_bounds__(256) void node_kernel(
  float* __restrict__ sf, u16* __restrict__ sbm,
  const u16* __restrict__ msg, const int* __restrict__ rowp, const int* __restrict__ eidx,
  const u16* __restrict__ w1s, const u16* __restrict__ w2s,
  const float* __restrict__ b1f, const float* __restrict__ b2f2, int b0)
{
  __shared__ __align__(16) u16 ninp[64 * 200];   // 192 + 8 pad (aligned 16B, 2-way banks)
  __shared__ __align__(16) u16 Yt[64 * 136];
  __shared__ float b1l[128];
  __shared__ float b2l[128];
  int tid = threadIdx.x;
  if (tid < 128) b1l[tid] = b1f[tid];
  else b2l[tid - 128] = b2f2[tid - 128];

  int bl = blockIdx.x / 157, nt = blockIdx.x % 157;
  int b = b0 + bl, n0 = nt * 64;

  { // gather incoming + copy states into ninp; 4 threads per node, 16 ch each
    int nl = tid >> 2, part = tid & 3;
    int n = n0 + nl;
    float acc[16];
    #pragma unroll
    for (int i = 0; i < 16; i++) acc[i] = 0.f;
    if (n < Nn){
      int r0 = rowp[n], r1 = rowp[n + 1];
      const u16* mb = msg + (((size_t)bl * Ee) << 6) + part * 16;
      for (int j = r0; j < r1; j++){
        int e = eidx[j];
        const uint4* mp = (const uint4*)(mb + ((size_t)e << 6));
        uint4 p0 = mp[0], p1 = mp[1];
        acc2bf(acc[0], acc[1], p0.x);  acc2bf(acc[2], acc[3], p0.y);
        acc2bf(acc[4], acc[5], p0.z);  acc2bf(acc[6], acc[7], p0.w);
        acc2bf(acc[8], acc[9], p1.x);  acc2bf(acc[10], acc[11], p1.y);
        acc2bf(acc[12], acc[13], p1.z); acc2bf(acc[14], acc[15], p1.w);
      }
    }
    union { u16 h[16]; uint4 v[2]; } tb;
    #pragma unroll
    for (int i = 0; i < 16; i++) tb.h[i] = f2b(acc[i]);
    *(uint4*)(ninp + nl * 200 + part * 16) = tb.v[0];
    *(uint4*)(ninp + nl * 200 + part * 16 + 8) = tb.v[1];
    uint4* dp = (uint4*)(ninp + nl * 200 + 64 + part * 32);
    if (n < Nn){
      const uint4* sp = (const uint4*)(sbm + (((size_t)b * Nn + n) << 7) + part * 32);
      #pragma unroll
      for (int i = 0; i < 4; i++) dp[i] = sp[i];
    } else {
      uint4 zz = {0, 0, 0, 0};
      #pragma unroll
      for (int i = 0; i < 4; i++) dp[i] = zz;
    }
  }
  __syncthreads();

  int w = tid >> 6, lane = tid & 63, m = lane & 15, quad = lane >> 4;
  const f32x4 z4 = {0.f, 0.f, 0.f, 0.f};
  f32x4 acc1[8];
  #pragma unroll
  for (int ct = 0; ct < 8; ct++) acc1[ct] = z4;
  #pragma unroll 1
  for (int ks = 0; ks < 6; ks++){
    bf16x8 a = *(const bf16x8*)(ninp + (w * 16 + m) * 200 + ks * 32 + quad * 8);
    #pragma unroll
    for (int ct = 0; ct < 8; ct++){
      bf16x8 bv = *(const bf16x8*)(w1s + (((ks * 4 + quad) << 7) + ct * 16 + m) * 8);
      acc1[ct] = __builtin_amdgcn_mfma_f32_16x16x32_bf16(a, bv, acc1[ct], 0, 0, 0);
    }
  }
  #pragma unroll
  for (int ct = 0; ct < 8; ct++){
    #pragma unroll
    for (int i = 0; i < 4; i++){
      float v = acc1[ct][i] + b1l[ct * 16 + m];
      v = v > 0.f ? v : 0.f;
      Yt[(w * 16 + quad * 4 + i) * 136 + ct * 16 + m] = f2b(v);
    }
  }
  f32x4 acc2[8];
  #pragma unroll
  for (int ct = 0; ct < 8; ct++) acc2[ct] = z4;
  #pragma unroll 1
  for (int ko = 0; ko < 4; ko++){
    bf16x8 a2 = *(const bf16x8*)(Yt + (w * 16 + m) * 136 + ko * 32 + quad * 8);
    #pragma unroll
    for (int ct = 0; ct < 8; ct++){
      bf16x8 bv = *(const bf16x8*)(w2s + (((ko * 4 + quad) << 7) + ct * 16 + m) * 8);
      acc2[ct] = __builtin_amdgcn_mfma_f32_16x16x32_bf16(a2, bv, acc2[ct], 0, 0, 0);
    }
  }
  // states[:, :, 2+u] += upd[u], keep f32 master + bf16 mirror in sync
  #pragma unroll
  for (int ct = 0; ct < 8; ct++){
    int u = ct * 16 + m;
    if (u < 126){
      #pragma unroll
      for (int i = 0; i < 4; i++){
        int n = n0 + w * 16 + quad * 4 + i;
        if (n < Nn){
          size_t idx = (((size_t)b * Nn + n) << 7) + 2 + u;
          float v = sf[idx] + acc2[ct][i] + b2l[u];
          sf[idx] = v;
          sbm[idx] = f2b(v);
        }
      }
    }
  }
}

// ---------------- extraction: partial sums over K-chunks of N ----------------
__global__ __launch_bounds__(256) void extract_kernel(
  const void* __restrict__ attn, const int* __restrict__ flag,
  const u16* __restrict__ sbm, float* __restrict__ part)
{
  __shared__ float at[16 * 128];
  int f = *flag;
  int blk = blockIdx.x;
  int kc = blk >> 6, rem = blk & 63;
  int b = rem >> 4, qt = rem & 15;
  int q0 = qt << 4;
  int tid = threadIdx.x;
  int d = tid & 127, qh = tid >> 7;
  float acc[8];
  #pragma unroll
  for (int i = 0; i < 8; i++) acc[i] = 0.f;
  int nbeg = kc * 1250;
  for (int s0 = 0; s0 < 1250; s0 += 128){
    __syncthreads();
    for (int i2 = tid; i2 < 2048; i2 += 256){
      int qi = i2 >> 7, ni = i2 & 127;
      int nn = s0 + ni;
      float v = 0.f;
      if (nn < 1250) v = ldin(attn, (long)(b * Qq + q0 + qi) * Nn + nbeg + nn, f);
      at[(qi << 7) + ni] = v;
    }
    __syncthreads();
    int lim = (1250 - s0 < 128) ? (1250 - s0) : 128;
    for (int ni = 0; ni < lim; ni++){
      float sv = b2f(sbm[(((size_t)b * Nn + nbeg + s0 + ni) << 7) + d]);
      #pragma unroll
      for (int i = 0; i < 8; i++) acc[i] += at[((qh * 8 + i) << 7) + ni] * sv;
    }
  }
  #pragma unroll
  for (int i = 0; i < 8; i++)
    part[(((size_t)(kc * 4 + b) * Qq + q0 + qh * 8 + i) << 7) + d] = acc[i];
}

// ---------------- finalize: out = [poses | sum(partials)] ----------------
__global__ void final_kernel(const void* __restrict__ poses, const int* __restrict__ flag,
                             const float* __restrict__ part, void* __restrict__ out)
{
  int f = *flag;
  const long total = (long)Bx * Qq * (Pp + Dd);
  for (long idx = (long)blockIdx.x * blockDim.x + threadIdx.x; idx < total; idx += (long)gridDim.x * blockDim.x){
    int j = (int)(idx % (Pp + Dd));
    long bq = idx / (Pp + Dd);
    float v;
    if (j < Pp){
      v = ldin(poses, bq * Pp + j, f);
    } else {
      int dd = j - Pp;
      int b = (int)(bq >> 8), q = (int)(bq & 255);
      v = 0.f;
      #pragma unroll
      for (int kc = 0; kc < 8; kc++)
        v += part[(((size_t)(kc * 4 + b) * Qq + q) << 7) + dd];
    }
    if (f) ((u16*)out)[idx] = f2b(v);
    else ((float*)out)[idx] = v;
  }
}

extern "C" void kernel_launch(void* const* d_in, const int* in_sizes, int n_in,
                              void* d_out, int out_size, void* d_ws, size_t ws_size,
                              hipStream_t stream)
{
  const void* in_states = d_in[0];
  const void* in_poses  = d_in[1];
  const void* in_attn   = d_in[2];
  const int*  in_src    = (const int*)d_in[3];
  const int*  in_snk    = (const int*)d_in[4];
  const void* in_w1e = d_in[5];  const void* in_b1e = d_in[6];
  const void* in_w2e = d_in[7];  const void* in_b2e = d_in[8];
  const void* in_w1n = d_in[9];  const void* in_b1n = d_in[10];
  const void* in_w2n = d_in[11]; const void* in_b2n = d_in[12];

  char* ws = (char*)d_ws;
  size_t off = 0;
  auto alloc = [&](size_t bytes){ size_t o = off; off = (off + bytes + 255) & ~(size_t)255; return o; };
  size_t o_sf   = alloc((size_t)Bx * Nn * Dd * 4);
  size_t o_sb   = alloc((size_t)Bx * Nn * Dd * 2);
  size_t o_rowp = alloc((size_t)(Nn + 1) * 4);
  size_t o_rcnt = alloc((size_t)Nn * 4);
  size_t o_eidx = alloc((size_t)Ee * 4);
  size_t o_part = alloc((size_t)8 * Bx * Qq * Dd * 4);
  size_t o_w1e  = alloc(32768 * 2);
  size_t o_w2e  = alloc(8192 * 2);
  size_t o_w1n  = alloc(24576 * 2);
  size_t o_w2n  = alloc(16384 * 2);
  size_t o_b1e  = alloc(128 * 4);
  size_t o_b2e  = alloc(64 * 4);
  size_t o_b1n  = alloc(128 * 4);
  size_t o_b2n  = alloc(128 * 4);
  size_t o_flag = alloc(4);
  size_t fixed = off;
  size_t msgPerB = (size_t)Ee * Mm * 2;
  int nb = (ws_size >= fixed + 4 * msgPerB + 256) ? 4 : 1;   // fall back to per-batch msg if ws is tight
  size_t o_msg = alloc((size_t)nb * msgPerB);

  float* sf    = (float*)(ws + o_sf);
  u16*   sbm   = (u16*)(ws + o_sb);
  int*   rowp  = (int*)(ws + o_rowp);
  int*   rcnt  = (int*)(ws + o_rcnt);
  int*   eidx  = (int*)(ws + o_eidx);
  float* part  = (float*)(ws + o_part);
  u16*   w1e_s = (u16*)(ws + o_w1e);
  u16*   w2e_s = (u16*)(ws + o_w2e);
  u16*   w1n_s = (u16*)(ws + o_w1n);
  u16*   w2n_s = (u16*)(ws + o_w2n);
  float* b1e_f = (float*)(ws + o_b1e);
  float* b2e_f = (float*)(ws + o_b2e);
  float* b1n_f = (float*)(ws + o_b1n);
  float* b2n_f = (float*)(ws + o_b2n);
  int*   flag  = (int*)(ws + o_flag);
  u16*   msg   = (u16*)(ws + o_msg);

  probe_kernel<<<1, 64, 0, stream>>>(in_states, flag);
  prep_kernel<<<322, 256, 0, stream>>>(in_w1e, in_b1e, in_w2e, in_b2e,
                                       in_w1n, in_b1n, in_w2n, in_b2n, flag,
                                       w1e_s, w2e_s, w1n_s, w2n_s,
                                       b1e_f, b2e_f, b1n_f, b2n_f);
  init_states_kernel<<<1024, 256, 0, stream>>>(in_states, flag, sf, sbm);

  hipMemsetAsync(rcnt, 0, (size_t)Nn * 4, stream);
  count_kernel<<<(Ee + 255) / 256, 256, 0, stream>>>(in_snk, rcnt);
  scan_kernel<<<1, 1024, 0, stream>>>(rcnt, rowp);
  hipMemsetAsync(rcnt, 0, (size_t)Nn * 4, stream);
  fill_kernel<<<(Ee + 255) / 256, 256, 0, stream>>>(in_snk, rowp, rcnt, eidx);

  for (int step = 0; step < 3; step++){
    for (int c = 0; c < 4 / nb; c++){
      int b0 = c * nb;
      edge_kernel<<<nb * 1250, 512, 0, stream>>>(sbm, in_src, in_snk, w1e_s, w2e_s,
                                                 b1e_f, b2e_f, msg, b0);
      node_kernel<<<nb * 157, 256, 0, stream>>>(sf, sbm, msg, rowp, eidx,
                                                w1n_s, w2n_s, b1n_f, b2n_f, b0);
    }
  }
  extract_kernel<<<512, 256, 0, stream>>>(in_attn, flag, sbm, part);
  final_kernel<<<540, 256, 0, stream>>>(in_poses, flag, part, d_out);
}